// Round 12
// baseline (350.156 us; speedup 1.0000x reference)
//
#include <hip/hip_runtime.h>
#include <hip/hip_bf16.h>

#define N_NODES   100000
#define N_EDGES   1600000
#define NUM_GRAPHS 1024
#define D         128
#define LN_EPS    1e-5f
#define NBUCKETS  391     // buckets of 256 nodes: bucket = dst >> 8
#define CAP       4864    // fixed bucket capacity (mean 4096 + 12 sigma); CAP/256 = 19
#define CHUNK     4096    // edges per bin_scatter block
#define ASTRIDE   288     // Asm row stride in shorts: 576B, 16B-aligned, word-stride%32==16 (m97 geometry)

typedef __attribute__((ext_vector_type(8))) short short8;
typedef __attribute__((ext_vector_type(4))) float floatx4;
typedef __attribute__((ext_vector_type(2))) float f32x2;

static __device__ __forceinline__ float bf2f(unsigned int u) {
    return __uint_as_float(u << 16);
}
static __device__ __forceinline__ unsigned short f2bf(float f) {
    __hip_bfloat16 h = __float2bfloat16(f);
    return *reinterpret_cast<unsigned short*>(&h);
}
// accumulate 8 bf16 channels (one uint4) into 4 packed fp32 pairs
static __device__ __forceinline__ void acc4(f32x2* acc, uint4 v) {
    acc[0] += (f32x2){__uint_as_float(v.x << 16), __uint_as_float(v.x & 0xffff0000u)};
    acc[1] += (f32x2){__uint_as_float(v.y << 16), __uint_as_float(v.y & 0xffff0000u)};
    acc[2] += (f32x2){__uint_as_float(v.z << 16), __uint_as_float(v.z & 0xffff0000u)};
    acc[3] += (f32x2){__uint_as_float(v.w << 16), __uint_as_float(v.w & 0xffff0000u)};
}

// ---- fused prep: x fp32->bf16, weight concat+cvt, bucket cursor init ----
__global__ __launch_bounds__(256)
void prep_kernel(const float* __restrict__ x, unsigned short* __restrict__ xbf,
                 const float* __restrict__ W1l, const float* __restrict__ W1r,
                 const float* __restrict__ W2l, const float* __restrict__ W2r,
                 unsigned short* __restrict__ Wc1, unsigned short* __restrict__ Wc2,
                 int* __restrict__ cursor) {
    int i = blockIdx.x * 256 + threadIdx.x;     // float4 index, 3.2M exact
    float4 v = reinterpret_cast<const float4*>(x)[i];
    ushort4 o;
    o.x = f2bf(v.x); o.y = f2bf(v.y); o.z = f2bf(v.z); o.w = f2bf(v.w);
    reinterpret_cast<ushort4*>(xbf)[i] = o;
    if (blockIdx.x < 256) {                     // 65536 weight elements
        int layer = i >> 15;
        int rem = i & 32767;
        int c = rem >> 8;
        int k = rem & 255;
        const float* Wl = layer ? W2l : W1l;
        const float* Wr = layer ? W2r : W1r;
        unsigned short* dst = layer ? Wc2 : Wc1;
        float wv = (k < 128) ? Wl[c * 128 + k] : Wr[c * 128 + (k - 128)];
        dst[c * 256 + k] = f2bf(wv);
    }
    if (blockIdx.x == 256) {
        for (int b = threadIdx.x; b < NBUCKETS; b += 256)
            cursor[b] = b * CAP;
    }
}

// ---- scatter edges into fixed-capacity dst buckets; 4B packed records ----
// rec = (dst&255)<<17 | src   (src < 2^17)
__global__ __launch_bounds__(256)
void bin_scatter_kernel(const int* __restrict__ src, const int* __restrict__ dst,
                        int* __restrict__ cursor, unsigned* __restrict__ binned) {
    __shared__ int cnt[NBUCKETS];
    __shared__ int base[NBUCKETS];
    int chunkBase = blockIdx.x * CHUNK;
    for (int i = threadIdx.x; i < NBUCKETS; i += 256) cnt[i] = 0;
    __syncthreads();
    int es[16], ed[16], lofs[16];
    #pragma unroll
    for (int j = 0; j < 16; ++j) {
        int e = chunkBase + j * 256 + threadIdx.x;
        if (e < N_EDGES) {
            es[j] = src[e];
            ed[j] = dst[e];
            lofs[j] = atomicAdd(&cnt[ed[j] >> 8], 1);
        }
    }
    __syncthreads();
    for (int i = threadIdx.x; i < NBUCKETS; i += 256) {
        int c = cnt[i];
        base[i] = c ? atomicAdd(&cursor[i], c) : 0;
    }
    __syncthreads();
    #pragma unroll
    for (int j = 0; j < 16; ++j) {
        int e = chunkBase + j * 256 + threadIdx.x;
        if (e < N_EDGES) {
            int b = ed[j] >> 8;
            int pos = base[b] + lofs[j];
            if (pos < (b + 1) * CAP)            // capacity guard (never hit at 12 sigma)
                binned[pos] = ((unsigned)(ed[j] & 255) << 17) | (unsigned)es[j];
        }
    }
}

// One block per bucket (256 nodes), SINGLE PASS over binned: records and
// within-node ranks cached in registers (<=19/thread); LDS count+scan; emit
// row_info (start,deg) and src_sorted.
__global__ __launch_bounds__(256)
void bucket_build_kernel(const unsigned* __restrict__ binned, const int* __restrict__ cursor,
                         int2* __restrict__ row_info, int* __restrict__ src_sorted) {
    __shared__ int scnt[256];
    __shared__ int sscan[256];
    int b = blockIdx.x;
    int t = threadIdx.x;
    int lo = b * CAP;
    int hi = cursor[b];                          // lo + bucket count
    int cap_end = lo + CAP;
    if (hi > cap_end) hi = cap_end;              // defense: never past window
    scnt[t] = 0;
    __syncthreads();
    unsigned rec[19];
    short rnk[19];
    #pragma unroll
    for (int i = 0; i < 19; ++i) {
        int e = lo + t + i * 256;
        if (e < hi) {
            unsigned r = binned[e];
            rec[i] = r;
            rnk[i] = (short)atomicAdd(&scnt[r >> 17], 1);
        }
    }
    __syncthreads();
    int v = scnt[t];
    sscan[t] = v;
    __syncthreads();
    for (int off = 1; off < 256; off <<= 1) {
        int a = (t >= off) ? sscan[t - off] : 0;
        __syncthreads();
        sscan[t] += a;
        __syncthreads();
    }
    int ex = sscan[t] - v;
    int node = b * 256 + t;
    if (node < N_NODES) row_info[node] = make_int2(lo + ex, v);
    scnt[t] = ex;                                // reuse as exclusive-prefix table
    __syncthreads();
    #pragma unroll
    for (int i = 0; i < 19; ++i) {
        int e = lo + t + i * 256;
        if (e < hi) {
            unsigned r = rec[i];
            src_sorted[lo + scnt[r >> 17] + rnk[i]] = (int)(r & 0x1FFFFu);
        }
    }
}

// ---- mean aggregation: wave = 1 node (plateau config, 58.7us) ----
__global__ __launch_bounds__(256)
void aggregate_kernel(const unsigned short* __restrict__ feat,
                      const int* __restrict__ src_sorted,
                      const int2* __restrict__ row_info,
                      unsigned short* __restrict__ aggout) {
    int wave = threadIdx.x >> 6;
    int lane = threadIdx.x & 63;
    int node = blockIdx.x * 4 + wave;
    int sub = lane >> 4;
    int ch = (lane & 15) * 8;
    int2 ri = row_info[node];
    int s = ri.x, deg = ri.y;
    const unsigned short* fb = feat + ch;
    f32x2 acc[4];
    acc[0] = acc[1] = acc[2] = acc[3] = (f32x2){0.f, 0.f};

    if (deg <= 64) {
        int si = 0;
        if (lane < deg) si = src_sorted[s + lane];
        int rounds = (deg + 3) >> 2;
        for (int r = 0; r < rounds; ++r) {
            int eidx = r * 4 + sub;
            int u = __shfl(si, eidx, 64);
            if (eidx < deg) {
                uint4 v = *(const uint4*)(fb + (size_t)u * 128);
                acc4(acc, v);
            }
        }
    } else {
        for (int j = s + sub; j < s + deg; j += 4) {
            int u = src_sorted[j];
            uint4 v = *(const uint4*)(fb + (size_t)u * 128);
            acc4(acc, v);
        }
    }
    #pragma unroll
    for (int i = 0; i < 4; ++i) {
        acc[i].x += __shfl_xor(acc[i].x, 16, 64);
        acc[i].y += __shfl_xor(acc[i].y, 16, 64);
        acc[i].x += __shfl_xor(acc[i].x, 32, 64);
        acc[i].y += __shfl_xor(acc[i].y, 32, 64);
    }
    float inv = 1.f / (float)(deg > 1 ? deg : 1);
    if (sub == 0) {
        uint4 ov;
        ov.x = (unsigned)f2bf(acc[0].x * inv) | ((unsigned)f2bf(acc[0].y * inv) << 16);
        ov.y = (unsigned)f2bf(acc[1].x * inv) | ((unsigned)f2bf(acc[1].y * inv) << 16);
        ov.z = (unsigned)f2bf(acc[2].x * inv) | ((unsigned)f2bf(acc[2].y * inv) << 16);
        ov.w = (unsigned)f2bf(acc[3].x * inv) | ((unsigned)f2bf(acc[3].y * inv) << 16);
        *(uint4*)(aggout + (size_t)node * 128 + ch) = ov;
    }
}

// ---- SAGE linear v3: single-barrier. A ([A1|A2] 64x256) staged ONCE in LDS;
// W frags preloaded to registers (L2-broadcast); k-loop = ds_read + MFMA only.
__global__ __launch_bounds__(256)
void gemm_kernel(const unsigned short* __restrict__ A1,   // k 0..127   (agg)
                 const unsigned short* __restrict__ A2,   // k 128..255 (self)
                 const unsigned short* __restrict__ Wcat, // [128][256] bf16 (B^T form)
                 const float* __restrict__ bias,
                 unsigned short* __restrict__ out) {
    __shared__ unsigned short Asm[64][ASTRIDE];  // 36.9 KB
    int tid = threadIdx.x;
    int wave = tid >> 6;
    int lane = tid & 63;
    int quad = lane >> 4, m = lane & 15;
    int nodeBase = blockIdx.x * 64;

    // W preload: 16 x 16B per lane, issued before staging so latency overlaps
    short8 bfr[8][2];
    #pragma unroll
    for (int kc = 0; kc < 8; ++kc)
        #pragma unroll
        for (int cb = 0; cb < 2; ++cb)
            bfr[kc][cb] = *(const short8*)(Wcat + (size_t)(wave * 32 + cb * 16 + m) * 256 + kc * 32 + quad * 8);

    // A staging: 64 rows x 256 k, 8 float4 per thread. cols [0,128)=A1, [128,256)=A2
    #pragma unroll
    for (int it = 0; it < 8; ++it) {
        int i = it * 256 + tid;
        int r = i >> 5;          // 32 float4 per row
        int c8 = i & 31;         // float4 index within row (8 shorts each)
        int node = nodeBase + r;
        float4 av = make_float4(0.f, 0.f, 0.f, 0.f);
        if (node < N_NODES) {
            const unsigned short* srcp = (c8 < 16)
                ? (A1 + (size_t)node * 128 + c8 * 8)
                : (A2 + (size_t)node * 128 + (c8 - 16) * 8);
            av = *(const float4*)srcp;
        }
        *(float4*)(&Asm[r][c8 * 8]) = av;
    }
    __syncthreads();

    floatx4 acc[4][2];
    #pragma unroll
    for (int a = 0; a < 4; ++a)
        #pragma unroll
        for (int b = 0; b < 2; ++b) acc[a][b] = (floatx4){0.f, 0.f, 0.f, 0.f};

    #pragma unroll
    for (int kc = 0; kc < 8; ++kc) {
        short8 afr[4];
        #pragma unroll
        for (int nb = 0; nb < 4; ++nb)
            afr[nb] = *(const short8*)(&Asm[nb * 16 + m][kc * 32 + quad * 8]);
        #pragma unroll
        for (int nb = 0; nb < 4; ++nb)
            #pragma unroll
            for (int cb = 0; cb < 2; ++cb)
                acc[nb][cb] = __builtin_amdgcn_mfma_f32_16x16x32_bf16(afr[nb], bfr[kc][cb], acc[nb][cb], 0, 0, 0);
    }
    #pragma unroll
    for (int cb = 0; cb < 2; ++cb) {
        int col = wave * 32 + cb * 16 + m;
        float bv = bias[col];
        #pragma unroll
        for (int nb = 0; nb < 4; ++nb) {
            #pragma unroll
            for (int rr = 0; rr < 4; ++rr) {
                int row = nodeBase + nb * 16 + quad * 4 + rr;
                if (row < N_NODES) {
                    float v = acc[nb][cb][rr] + bv;
                    v = v > 0.f ? v : 0.f;
                    out[(size_t)row * 128 + col] = f2bf(v);
                }
            }
        }
    }
}

// ---- global_add_pool + LayerNorm + linear head (vectorized loads) ----
__global__ __launch_bounds__(256)
void pool_ln_out_kernel(const unsigned short* __restrict__ h2,
                        const int* __restrict__ batch,
                        const float* __restrict__ ln_g, const float* __restrict__ ln_b,
                        const float* __restrict__ Wlin, const float* __restrict__ blin,
                        float* __restrict__ out) {
    int g = blockIdx.x;
    int t = threadIdx.x;   // 256 threads
    int lane = t & 63, w = t >> 6;
    __shared__ int se[2];
    if (t < 2) {
        int target = g + t;
        int lo = 0, hi = N_NODES;
        while (lo < hi) {
            int mid = (lo + hi) >> 1;
            if (batch[mid] < target) lo = mid + 1; else hi = mid;
        }
        se[t] = lo;
    }
    __syncthreads();
    int s = se[0], e = se[1];
    int ns = t >> 4;       // 0..15 node stripe
    int chg = t & 15;      // channel group (8 ch)
    f32x2 a[4];
    a[0] = a[1] = a[2] = a[3] = (f32x2){0.f, 0.f};
    for (int n = s + ns; n < e; n += 16) {
        uint4 v = *(const uint4*)(h2 + (size_t)n * 128 + chg * 8);
        acc4(a, v);
    }
    #pragma unroll
    for (int i = 0; i < 4; ++i) {
        a[i].x += __shfl_xor(a[i].x, 16, 64);
        a[i].y += __shfl_xor(a[i].y, 16, 64);
        a[i].x += __shfl_xor(a[i].x, 32, 64);
        a[i].y += __shfl_xor(a[i].y, 32, 64);
    }
    __shared__ float sw[4][128];
    if (lane < 16) {
        #pragma unroll
        for (int k = 0; k < 4; ++k) {
            sw[w][chg * 8 + 2 * k]     = a[k].x;
            sw[w][chg * 8 + 2 * k + 1] = a[k].y;
        }
    }
    __syncthreads();
    __shared__ float red[128];
    float sum = 0.f;
    if (t < 128) {
        sum = sw[0][t] + sw[1][t] + sw[2][t] + sw[3][t];
        red[t] = sum;
    }
    __syncthreads();
    for (int off = 64; off > 0; off >>= 1) {
        if (t < off) red[t] += red[t + off];
        __syncthreads();
    }
    float mu = red[0] * (1.f / 128.f);
    __syncthreads();
    float dv = sum - mu;
    if (t < 128) red[t] = dv * dv;
    __syncthreads();
    for (int off = 64; off > 0; off >>= 1) {
        if (t < off) red[t] += red[t + off];
        __syncthreads();
    }
    float var = red[0] * (1.f / 128.f);
    __syncthreads();
    __shared__ float r0[128], r1[128];
    if (t < 128) {
        float gn = dv * rsqrtf(var + LN_EPS) * ln_g[t] + ln_b[t];
        r0[t] = gn * Wlin[t];
        r1[t] = gn * Wlin[128 + t];
    }
    __syncthreads();
    for (int off = 64; off > 0; off >>= 1) {
        if (t < off) { r0[t] += r0[t + off]; r1[t] += r1[t + off]; }
        __syncthreads();
    }
    if (t == 0) {
        out[g * 2 + 0] = r0[0] + blin[0];
        out[g * 2 + 1] = r1[0] + blin[1];
    }
}

extern "C" void kernel_launch(void* const* d_in, const int* in_sizes, int n_in,
                              void* d_out, int out_size, void* d_ws, size_t ws_size,
                              hipStream_t stream) {
    const float* x    = (const float*)d_in[0];
    const int*   ei   = (const int*)d_in[1];
    const int*   batch= (const int*)d_in[2];
    const float* W1l  = (const float*)d_in[3];
    const float* b1l  = (const float*)d_in[4];
    const float* W1r  = (const float*)d_in[5];
    const float* W2l  = (const float*)d_in[6];
    const float* b2l  = (const float*)d_in[7];
    const float* W2r  = (const float*)d_in[8];
    const float* ln_g = (const float*)d_in[9];
    const float* ln_b = (const float*)d_in[10];
    const float* Wlin = (const float*)d_in[11];
    const float* blin = (const float*)d_in[12];
    float* out = (float*)d_out;

    char* ws = (char*)d_ws;
    size_t off = 0;
    auto alloc = [&](size_t bytes) {
        char* p = ws + off;
        off = (off + bytes + 255) & ~(size_t)255;
        return p;
    };
    unsigned short* xbf  = (unsigned short*)alloc((size_t)N_NODES * D * 2); // later reused for h2
    unsigned short* aggb = (unsigned short*)alloc((size_t)N_NODES * D * 2); // aliased by binned
    unsigned short* h1   = (unsigned short*)alloc((size_t)N_NODES * D * 2);
    unsigned short* Wc1  = (unsigned short*)alloc(128 * 256 * 2);
    unsigned short* Wc2  = (unsigned short*)alloc(128 * 256 * 2);
    int2* row_info   = (int2*)alloc((size_t)N_NODES * 8);
    int* src_sorted  = (int*)alloc((size_t)NBUCKETS * CAP * 4);
    int* cursor      = (int*)alloc(NBUCKETS * 4);
    unsigned* binned = (unsigned*)aggb;   // 7.6 MB <= 25.6 MB; consumed before aggb written

    const int* srcI = ei;            // edge_index[0]
    const int* dstI = ei + N_EDGES;  // edge_index[1]

    prep_kernel<<<12500, 256, 0, stream>>>(x, xbf, W1l, W1r, W2l, W2r, Wc1, Wc2, cursor);
    bin_scatter_kernel<<<(N_EDGES + CHUNK - 1) / CHUNK, 256, 0, stream>>>(srcI, dstI, cursor, binned);
    bucket_build_kernel<<<NBUCKETS, 256, 0, stream>>>(binned, cursor, row_info, src_sorted);

    aggregate_kernel<<<25000, 256, 0, stream>>>(xbf, src_sorted, row_info, aggb);
    gemm_kernel<<<1563, 256, 0, stream>>>(aggb, xbf, Wc1, b1l, h1);
    aggregate_kernel<<<25000, 256, 0, stream>>>(h1, src_sorted, row_info, aggb);
    gemm_kernel<<<1563, 256, 0, stream>>>(aggb, h1, Wc2, b2l, xbf);
    pool_ln_out_kernel<<<NUM_GRAPHS, 256, 0, stream>>>(xbf, batch, ln_g, ln_b, Wlin, blin, out);
}

// Round 13
// 320.541 us; speedup vs baseline: 1.0924x; 1.0924x over previous
//
#include <hip/hip_runtime.h>
#include <hip/hip_bf16.h>
#include <hip/hip_fp8.h>

#define N_NODES   100000
#define N_EDGES   1600000
#define NUM_GRAPHS 1024
#define D         128
#define LN_EPS    1e-5f
#define NBUCKETS  391     // buckets of 256 nodes: bucket = dst >> 8
#define CAP       4864    // fixed bucket capacity (mean 4096 + 12 sigma); CAP/256 = 19
#define CHUNK     4096    // edges per bin_scatter block

typedef __attribute__((ext_vector_type(8))) short short8;
typedef __attribute__((ext_vector_type(4))) float floatx4;
typedef __attribute__((ext_vector_type(2))) float f32x2;

static __device__ __forceinline__ float bf2f(unsigned int u) {
    return __uint_as_float(u << 16);
}
static __device__ __forceinline__ unsigned short f2bf(float f) {
    __hip_bfloat16 h = __float2bfloat16(f);
    return *reinterpret_cast<unsigned short*>(&h);
}
// accumulate 8 bf16 channels (one uint4) into 4 packed fp32 pairs
static __device__ __forceinline__ void acc4(f32x2* acc, uint4 v) {
    acc[0] += (f32x2){__uint_as_float(v.x << 16), __uint_as_float(v.x & 0xffff0000u)};
    acc[1] += (f32x2){__uint_as_float(v.y << 16), __uint_as_float(v.y & 0xffff0000u)};
    acc[2] += (f32x2){__uint_as_float(v.z << 16), __uint_as_float(v.z & 0xffff0000u)};
    acc[3] += (f32x2){__uint_as_float(v.w << 16), __uint_as_float(v.w & 0xffff0000u)};
}

// ---- fp8 e4m3 (OCP) pack/unpack ----
#if __has_builtin(__builtin_amdgcn_cvt_pk_f32_fp8)
#define UNPK_FP8(x, w) __builtin_amdgcn_cvt_pk_f32_fp8((x), (w))
#else
static __device__ __forceinline__ f32x2 unpk_fp8_sw(unsigned x, bool w) {
    unsigned s = w ? (x >> 16) : (x & 0xffffu);
    __hip_fp8_e4m3 a, b;
    *reinterpret_cast<unsigned char*>(&a) = (unsigned char)(s & 0xff);
    *reinterpret_cast<unsigned char*>(&b) = (unsigned char)((s >> 8) & 0xff);
    return (f32x2){(float)a, (float)b};
}
#define UNPK_FP8(x, w) unpk_fp8_sw((x), (w))
#endif

#if __has_builtin(__builtin_amdgcn_cvt_pk_fp8_f32)
#define PK_FP8(a, b, old, w) ((unsigned)__builtin_amdgcn_cvt_pk_fp8_f32((a), (b), (int)(old), (w)))
#else
static __device__ __forceinline__ unsigned pk_fp8_sw(float a, float b) {
    __hip_fp8_e4m3 fa = (__hip_fp8_e4m3)a;
    __hip_fp8_e4m3 fb = (__hip_fp8_e4m3)b;
    return (unsigned)*reinterpret_cast<unsigned char*>(&fa) |
           ((unsigned)*reinterpret_cast<unsigned char*>(&fb) << 8);
}
#define PK_FP8(a, b, old, w) ((w) ? ((((unsigned)(old)) & 0xffffu) | (pk_fp8_sw((a),(b)) << 16)) \
                                  : ((((unsigned)(old)) & 0xffff0000u) | pk_fp8_sw((a),(b))))
#endif

// ---- fused prep: x -> bf16 + fp8 tables, weight concat+cvt, cursor init ----
__global__ __launch_bounds__(256)
void prep_kernel(const float* __restrict__ x, unsigned short* __restrict__ xbf,
                 unsigned* __restrict__ xf8,
                 const float* __restrict__ W1l, const float* __restrict__ W1r,
                 const float* __restrict__ W2l, const float* __restrict__ W2r,
                 unsigned short* __restrict__ Wc1, unsigned short* __restrict__ Wc2,
                 int* __restrict__ cursor) {
    int i = blockIdx.x * 256 + threadIdx.x;     // float4 index, 3.2M exact
    float4 v = reinterpret_cast<const float4*>(x)[i];
    ushort4 o;
    o.x = f2bf(v.x); o.y = f2bf(v.y); o.z = f2bf(v.z); o.w = f2bf(v.w);
    reinterpret_cast<ushort4*>(xbf)[i] = o;
    unsigned p = PK_FP8(v.x, v.y, 0u, false);
    p = PK_FP8(v.z, v.w, p, true);
    xf8[i] = p;                                 // 4 fp8 bytes, coalesced
    if (blockIdx.x < 256) {                     // 65536 weight elements
        int layer = i >> 15;
        int rem = i & 32767;
        int c = rem >> 8;
        int k = rem & 255;
        const float* Wl = layer ? W2l : W1l;
        const float* Wr = layer ? W2r : W1r;
        unsigned short* dst = layer ? Wc2 : Wc1;
        float wv = (k < 128) ? Wl[c * 128 + k] : Wr[c * 128 + (k - 128)];
        dst[c * 256 + k] = f2bf(wv);
    }
    if (blockIdx.x == 256) {
        for (int b = threadIdx.x; b < NBUCKETS; b += 256)
            cursor[b] = b * CAP;
    }
}

// ---- h1 bf16 -> fp8 table (coalesced, 8 ch per thread) ----
__global__ __launch_bounds__(256)
void cvt_h1_kernel(const unsigned short* __restrict__ h1, uint2* __restrict__ h1f8) {
    int i = blockIdx.x * 256 + threadIdx.x;     // 8-ch group, 1.6M exact
    uint4 v = reinterpret_cast<const uint4*>(h1)[i];
    float c0 = __uint_as_float(v.x << 16), c1 = __uint_as_float(v.x & 0xffff0000u);
    float c2 = __uint_as_float(v.y << 16), c3 = __uint_as_float(v.y & 0xffff0000u);
    float c4 = __uint_as_float(v.z << 16), c5 = __uint_as_float(v.z & 0xffff0000u);
    float c6 = __uint_as_float(v.w << 16), c7 = __uint_as_float(v.w & 0xffff0000u);
    unsigned lo = PK_FP8(c0, c1, 0u, false);
    lo = PK_FP8(c2, c3, lo, true);
    unsigned hi = PK_FP8(c4, c5, 0u, false);
    hi = PK_FP8(c6, c7, hi, true);
    h1f8[i] = make_uint2(lo, hi);
}

// ---- scatter edges into fixed-capacity dst buckets; 4B packed records ----
// rec = (dst&255)<<17 | src   (src < 2^17)
__global__ __launch_bounds__(256)
void bin_scatter_kernel(const int* __restrict__ src, const int* __restrict__ dst,
                        int* __restrict__ cursor, unsigned* __restrict__ binned) {
    __shared__ int cnt[NBUCKETS];
    __shared__ int base[NBUCKETS];
    int chunkBase = blockIdx.x * CHUNK;
    for (int i = threadIdx.x; i < NBUCKETS; i += 256) cnt[i] = 0;
    __syncthreads();
    int es[16], ed[16], lofs[16];
    #pragma unroll
    for (int j = 0; j < 16; ++j) {
        int e = chunkBase + j * 256 + threadIdx.x;
        if (e < N_EDGES) {
            es[j] = src[e];
            ed[j] = dst[e];
            lofs[j] = atomicAdd(&cnt[ed[j] >> 8], 1);
        }
    }
    __syncthreads();
    for (int i = threadIdx.x; i < NBUCKETS; i += 256) {
        int c = cnt[i];
        base[i] = c ? atomicAdd(&cursor[i], c) : 0;
    }
    __syncthreads();
    #pragma unroll
    for (int j = 0; j < 16; ++j) {
        int e = chunkBase + j * 256 + threadIdx.x;
        if (e < N_EDGES) {
            int b = ed[j] >> 8;
            int pos = base[b] + lofs[j];
            if (pos < (b + 1) * CAP)            // capacity guard (never hit at 12 sigma)
                binned[pos] = ((unsigned)(ed[j] & 255) << 17) | (unsigned)es[j];
        }
    }
}

// One block per bucket (256 nodes), single pass: records + ranks in registers.
__global__ __launch_bounds__(256)
void bucket_build_kernel(const unsigned* __restrict__ binned, const int* __restrict__ cursor,
                         int2* __restrict__ row_info, int* __restrict__ src_sorted) {
    __shared__ int scnt[256];
    __shared__ int sscan[256];
    int b = blockIdx.x;
    int t = threadIdx.x;
    int lo = b * CAP;
    int hi = cursor[b];
    int cap_end = lo + CAP;
    if (hi > cap_end) hi = cap_end;
    scnt[t] = 0;
    __syncthreads();
    unsigned rec[19];
    short rnk[19];
    #pragma unroll
    for (int i = 0; i < 19; ++i) {
        int e = lo + t + i * 256;
        if (e < hi) {
            unsigned r = binned[e];
            rec[i] = r;
            rnk[i] = (short)atomicAdd(&scnt[r >> 17], 1);
        }
    }
    __syncthreads();
    int v = scnt[t];
    sscan[t] = v;
    __syncthreads();
    for (int off = 1; off < 256; off <<= 1) {
        int a = (t >= off) ? sscan[t - off] : 0;
        __syncthreads();
        sscan[t] += a;
        __syncthreads();
    }
    int ex = sscan[t] - v;
    int node = b * 256 + t;
    if (node < N_NODES) row_info[node] = make_int2(lo + ex, v);
    scnt[t] = ex;
    __syncthreads();
    #pragma unroll
    for (int i = 0; i < 19; ++i) {
        int e = lo + t + i * 256;
        if (e < hi) {
            unsigned r = rec[i];
            src_sorted[lo + scnt[r >> 17] + rnk[i]] = (int)(r & 0x1FFFFu);
        }
    }
}

// ---- mean aggregation from fp8 table: wave = 1 node; rows are 128B (2 lines) ----
__global__ __launch_bounds__(256)
void aggregate_kernel(const unsigned char* __restrict__ feat8,
                      const int* __restrict__ src_sorted,
                      const int2* __restrict__ row_info,
                      unsigned short* __restrict__ aggout) {
    int wave = threadIdx.x >> 6;
    int lane = threadIdx.x & 63;
    int node = blockIdx.x * 4 + wave;
    int sub = lane >> 4;
    int ch = (lane & 15) * 8;
    int2 ri = row_info[node];
    int s = ri.x, deg = ri.y;
    const unsigned char* fb = feat8 + ch;
    f32x2 acc[4];
    acc[0] = acc[1] = acc[2] = acc[3] = (f32x2){0.f, 0.f};

    if (deg <= 64) {
        int si = 0;
        if (lane < deg) si = src_sorted[s + lane];
        int rounds = (deg + 3) >> 2;
        for (int r = 0; r < rounds; ++r) {
            int eidx = r * 4 + sub;
            int u = __shfl(si, eidx, 64);
            if (eidx < deg) {
                uint2 v = *(const uint2*)(fb + (size_t)u * 128);
                acc[0] += UNPK_FP8(v.x, false);
                acc[1] += UNPK_FP8(v.x, true);
                acc[2] += UNPK_FP8(v.y, false);
                acc[3] += UNPK_FP8(v.y, true);
            }
        }
    } else {
        for (int j = s + sub; j < s + deg; j += 4) {
            int u = src_sorted[j];
            uint2 v = *(const uint2*)(fb + (size_t)u * 128);
            acc[0] += UNPK_FP8(v.x, false);
            acc[1] += UNPK_FP8(v.x, true);
            acc[2] += UNPK_FP8(v.y, false);
            acc[3] += UNPK_FP8(v.y, true);
        }
    }
    #pragma unroll
    for (int i = 0; i < 4; ++i) {
        acc[i].x += __shfl_xor(acc[i].x, 16, 64);
        acc[i].y += __shfl_xor(acc[i].y, 16, 64);
        acc[i].x += __shfl_xor(acc[i].x, 32, 64);
        acc[i].y += __shfl_xor(acc[i].y, 32, 64);
    }
    float inv = 1.f / (float)(deg > 1 ? deg : 1);
    if (sub == 0) {
        uint4 ov;
        ov.x = (unsigned)f2bf(acc[0].x * inv) | ((unsigned)f2bf(acc[0].y * inv) << 16);
        ov.y = (unsigned)f2bf(acc[1].x * inv) | ((unsigned)f2bf(acc[1].y * inv) << 16);
        ov.z = (unsigned)f2bf(acc[2].x * inv) | ((unsigned)f2bf(acc[2].y * inv) << 16);
        ov.w = (unsigned)f2bf(acc[3].x * inv) | ((unsigned)f2bf(acc[3].y * inv) << 16);
        *(uint4*)(aggout + (size_t)node * 128 + ch) = ov;
    }
}

// ---- fused SAGE linear (R11-verified v2): relu([A1|A2]@Wcat^T+b), bf16 MFMA ----
__global__ __launch_bounds__(256)
void gemm_kernel(const unsigned short* __restrict__ A1,   // k 0..127   (agg)
                 const unsigned short* __restrict__ A2,   // k 128..255 (self)
                 const unsigned short* __restrict__ Wcat, // [128][256] bf16 (B^T form)
                 const float* __restrict__ bias,
                 unsigned short* __restrict__ out) {
    __shared__ unsigned short Asm[64][32];
    __shared__ unsigned short Wsm[128][32];
    int tid = threadIdx.x;
    int wave = tid >> 6;
    int lane = tid & 63;
    int nodeBase = blockIdx.x * 64;
    floatx4 acc[4][2];
    #pragma unroll
    for (int a = 0; a < 4; ++a)
        #pragma unroll
        for (int b = 0; b < 2; ++b) acc[a][b] = (floatx4){0.f, 0.f, 0.f, 0.f};

    int r = tid >> 2, sg = tid & 3;
    int quad = lane >> 4, m = lane & 15;

    for (int kc = 0; kc < 8; ++kc) {
        const unsigned short* Asrc = (kc < 4) ? A1 : A2;
        int kOff = (kc & 3) * 32;
        int node = nodeBase + r;
        float4 av = make_float4(0.f, 0.f, 0.f, 0.f);
        if (node < N_NODES) av = *(const float4*)(Asrc + (size_t)node * 128 + kOff + sg * 8);
        *(float4*)(&Asm[r][sg * 8]) = av;
        #pragma unroll
        for (int it = 0; it < 2; ++it) {
            int idx = tid + it * 256;
            int wr = idx >> 2, wsg = idx & 3;
            *(float4*)(&Wsm[wr][wsg * 8]) = *(const float4*)(Wcat + wr * 256 + kc * 32 + wsg * 8);
        }
        __syncthreads();
        short8 afr[4], bfr[2];
        #pragma unroll
        for (int nb = 0; nb < 4; ++nb)
            afr[nb] = *(const short8*)(&Asm[nb * 16 + m][quad * 8]);
        #pragma unroll
        for (int cb = 0; cb < 2; ++cb)
            bfr[cb] = *(const short8*)(&Wsm[wave * 32 + cb * 16 + m][quad * 8]);
        #pragma unroll
        for (int nb = 0; nb < 4; ++nb)
            #pragma unroll
            for (int cb = 0; cb < 2; ++cb)
                acc[nb][cb] = __builtin_amdgcn_mfma_f32_16x16x32_bf16(afr[nb], bfr[cb], acc[nb][cb], 0, 0, 0);
        __syncthreads();
    }
    #pragma unroll
    for (int cb = 0; cb < 2; ++cb) {
        int col = wave * 32 + cb * 16 + m;
        float bv = bias[col];
        #pragma unroll
        for (int nb = 0; nb < 4; ++nb) {
            #pragma unroll
            for (int rr = 0; rr < 4; ++rr) {
                int row = nodeBase + nb * 16 + quad * 4 + rr;
                if (row < N_NODES) {
                    float v = acc[nb][cb][rr] + bv;
                    v = v > 0.f ? v : 0.f;
                    out[(size_t)row * 128 + col] = f2bf(v);
                }
            }
        }
    }
}

// ---- global_add_pool + LayerNorm + linear head (vectorized loads) ----
__global__ __launch_bounds__(256)
void pool_ln_out_kernel(const unsigned short* __restrict__ h2,
                        const int* __restrict__ batch,
                        const float* __restrict__ ln_g, const float* __restrict__ ln_b,
                        const float* __restrict__ Wlin, const float* __restrict__ blin,
                        float* __restrict__ out) {
    int g = blockIdx.x;
    int t = threadIdx.x;   // 256 threads
    int lane = t & 63, w = t >> 6;
    __shared__ int se[2];
    if (t < 2) {
        int target = g + t;
        int lo = 0, hi = N_NODES;
        while (lo < hi) {
            int mid = (lo + hi) >> 1;
            if (batch[mid] < target) lo = mid + 1; else hi = mid;
        }
        se[t] = lo;
    }
    __syncthreads();
    int s = se[0], e = se[1];
    int ns = t >> 4;       // 0..15 node stripe
    int chg = t & 15;      // channel group (8 ch)
    f32x2 a[4];
    a[0] = a[1] = a[2] = a[3] = (f32x2){0.f, 0.f};
    for (int n = s + ns; n < e; n += 16) {
        uint4 v = *(const uint4*)(h2 + (size_t)n * 128 + chg * 8);
        acc4(a, v);
    }
    #pragma unroll
    for (int i = 0; i < 4; ++i) {
        a[i].x += __shfl_xor(a[i].x, 16, 64);
        a[i].y += __shfl_xor(a[i].y, 16, 64);
        a[i].x += __shfl_xor(a[i].x, 32, 64);
        a[i].y += __shfl_xor(a[i].y, 32, 64);
    }
    __shared__ float sw[4][128];
    if (lane < 16) {
        #pragma unroll
        for (int k = 0; k < 4; ++k) {
            sw[w][chg * 8 + 2 * k]     = a[k].x;
            sw[w][chg * 8 + 2 * k + 1] = a[k].y;
        }
    }
    __syncthreads();
    __shared__ float red[128];
    float sum = 0.f;
    if (t < 128) {
        sum = sw[0][t] + sw[1][t] + sw[2][t] + sw[3][t];
        red[t] = sum;
    }
    __syncthreads();
    for (int off = 64; off > 0; off >>= 1) {
        if (t < off) red[t] += red[t + off];
        __syncthreads();
    }
    float mu = red[0] * (1.f / 128.f);
    __syncthreads();
    float dv = sum - mu;
    if (t < 128) red[t] = dv * dv;
    __syncthreads();
    for (int off = 64; off > 0; off >>= 1) {
        if (t < off) red[t] += red[t + off];
        __syncthreads();
    }
    float var = red[0] * (1.f / 128.f);
    __syncthreads();
    __shared__ float r0[128], r1[128];
    if (t < 128) {
        float gn = dv * rsqrtf(var + LN_EPS) * ln_g[t] + ln_b[t];
        r0[t] = gn * Wlin[t];
        r1[t] = gn * Wlin[128 + t];
    }
    __syncthreads();
    for (int off = 64; off > 0; off >>= 1) {
        if (t < off) { r0[t] += r0[t + off]; r1[t] += r1[t + off]; }
        __syncthreads();
    }
    if (t == 0) {
        out[g * 2 + 0] = r0[0] + blin[0];
        out[g * 2 + 1] = r1[0] + blin[1];
    }
}

extern "C" void kernel_launch(void* const* d_in, const int* in_sizes, int n_in,
                              void* d_out, int out_size, void* d_ws, size_t ws_size,
                              hipStream_t stream) {
    const float* x    = (const float*)d_in[0];
    const int*   ei   = (const int*)d_in[1];
    const int*   batch= (const int*)d_in[2];
    const float* W1l  = (const float*)d_in[3];
    const float* b1l  = (const float*)d_in[4];
    const float* W1r  = (const float*)d_in[5];
    const float* W2l  = (const float*)d_in[6];
    const float* b2l  = (const float*)d_in[7];
    const float* W2r  = (const float*)d_in[8];
    const float* ln_g = (const float*)d_in[9];
    const float* ln_b = (const float*)d_in[10];
    const float* Wlin = (const float*)d_in[11];
    const float* blin = (const float*)d_in[12];
    float* out = (float*)d_out;

    char* ws = (char*)d_ws;
    size_t off = 0;
    auto alloc = [&](size_t bytes) {
        char* p = ws + off;
        off = (off + bytes + 255) & ~(size_t)255;
        return p;
    };
    unsigned short* xbf  = (unsigned short*)alloc((size_t)N_NODES * D * 2); // later reused for h2
    unsigned short* aggb = (unsigned short*)alloc((size_t)N_NODES * D * 2); // aliased by binned
    unsigned short* h1   = (unsigned short*)alloc((size_t)N_NODES * D * 2);
    unsigned*       xf8  = (unsigned*)alloc((size_t)N_NODES * D);           // fp8 x table; reused as h1f8
    unsigned short* Wc1  = (unsigned short*)alloc(128 * 256 * 2);
    unsigned short* Wc2  = (unsigned short*)alloc(128 * 256 * 2);
    int2* row_info   = (int2*)alloc((size_t)N_NODES * 8);
    int* src_sorted  = (int*)alloc((size_t)NBUCKETS * CAP * 4);
    int* cursor      = (int*)alloc(NBUCKETS * 4);
    unsigned* binned = (unsigned*)aggb;   // 7.6 MB <= 25.6 MB; consumed before aggb written
    uint2* h1f8      = (uint2*)xf8;       // xf8 dead after aggregate1

    const int* srcI = ei;            // edge_index[0]
    const int* dstI = ei + N_EDGES;  // edge_index[1]

    prep_kernel<<<12500, 256, 0, stream>>>(x, xbf, xf8, W1l, W1r, W2l, W2r, Wc1, Wc2, cursor);
    bin_scatter_kernel<<<(N_EDGES + CHUNK - 1) / CHUNK, 256, 0, stream>>>(srcI, dstI, cursor, binned);
    bucket_build_kernel<<<NBUCKETS, 256, 0, stream>>>(binned, cursor, row_info, src_sorted);

    aggregate_kernel<<<25000, 256, 0, stream>>>((const unsigned char*)xf8, src_sorted, row_info, aggb);
    gemm_kernel<<<1563, 256, 0, stream>>>(aggb, xbf, Wc1, b1l, h1);
    cvt_h1_kernel<<<6250, 256, 0, stream>>>(h1, h1f8);
    aggregate_kernel<<<25000, 256, 0, stream>>>((const unsigned char*)h1f8, src_sorted, row_info, aggb);
    gemm_kernel<<<1563, 256, 0, stream>>>(aggb, h1, Wc2, b2l, xbf);
    pool_ln_out_kernel<<<NUM_GRAPHS, 256, 0, stream>>>(xbf, batch, ln_g, ln_b, Wlin, blin, out);
}